// Round 1
// baseline (261.776 us; speedup 1.0000x reference)
//
#include <hip/hip_runtime.h>

typedef _Float16 f16x8 __attribute__((ext_vector_type(8)));
typedef _Float16 f16x4 __attribute__((ext_vector_type(4)));
typedef float    f32x4 __attribute__((ext_vector_type(4)));

namespace {
constexpr int kH = 16, kL = 2048, kD = 64;
constexpr int QBLK  = 128;   // q rows per block (4 waves x 32 rows)
constexpr int KVBLK = 64;    // kv rows per tile
constexpr int PAD   = 72;    // halves per LDS row (144 B: 16B-aligned, bank-spread)
constexpr int NWAVE = 4;
}

__global__ __launch_bounds__(256, 2)
void attn_fwd(const float* __restrict__ Qg, const float* __restrict__ Kg,
              const float* __restrict__ Vg, float* __restrict__ Og)
{
    __shared__ _Float16 sK[KVBLK][PAD];
    __shared__ _Float16 sV[kD][PAD];            // V transposed: sV[d][kv]
    __shared__ _Float16 sP[NWAVE][2][16][PAD];  // per-wave, per-rowgroup P

    const int tid  = threadIdx.x;
    const int wv   = tid >> 6;
    const int lane = tid & 63;
    const int lo   = lane & 15;
    const int hi   = lane >> 4;

    // XCD-aware swizzle: 1024 blocks, 8 XCDs; all 16 q-tiles of a head share an XCD.
    const int blk  = blockIdx.x;
    const int bh   = (blk & 7) * 8 + (blk >> 7);   // 0..63
    const int qt   = (blk >> 3) & 15;              // 0..15
    const int q0   = qt * QBLK;
    const int b    = bh >> 4;
    const int h    = bh & 15;

    const float QS = 0.125f * 1.44269504088896340736f;  // scale * log2(e)

    // ---- Q fragments in registers: A-frag(lane,j) = Q[lo][(hi*8+j) + 32*slab] ----
    f16x8 qf[2][2];  // [row-group][k-slab]
    #pragma unroll
    for (int g = 0; g < 2; ++g) {
        const float* qb = Qg + ((size_t)bh * kL + (q0 + wv*32 + g*16 + lo)) * kD;
        #pragma unroll
        for (int s = 0; s < 2; ++s) {
            const float* p = qb + s*32 + hi*8;
            float4 a0 = *(const float4*)(p);
            float4 a1 = *(const float4*)(p + 4);
            f16x8 q;
            q[0] = (_Float16)(a0.x * QS); q[1] = (_Float16)(a0.y * QS);
            q[2] = (_Float16)(a0.z * QS); q[3] = (_Float16)(a0.w * QS);
            q[4] = (_Float16)(a1.x * QS); q[5] = (_Float16)(a1.y * QS);
            q[6] = (_Float16)(a1.z * QS); q[7] = (_Float16)(a1.w * QS);
            qf[g][s] = q;
        }
    }

    f32x4 acc[2][4];
    #pragma unroll
    for (int g = 0; g < 2; ++g)
        #pragma unroll
        for (int dt = 0; dt < 4; ++dt) acc[g][dt] = (f32x4){0.f, 0.f, 0.f, 0.f};

    float mrow[2][4], lrow[2][4];
    #pragma unroll
    for (int g = 0; g < 2; ++g)
        #pragma unroll
        for (int r = 0; r < 4; ++r) { mrow[g][r] = -1e30f; lrow[g][r] = 0.f; }

    const float* kb = Kg + (size_t)bh * kL * kD;
    const float* vb = Vg + (size_t)bh * kL * kD;

    for (int kv = 0; kv < kL; kv += KVBLK) {
        __syncthreads();
        // ---- stage K tile (row-major, fp32 -> fp16) ----
        {
            const float4* src = (const float4*)(kb + (size_t)kv * kD);
            #pragma unroll
            for (int i = 0; i < 4; ++i) {
                int f   = tid + i * 256;   // float4 index in contiguous 64x64 tile
                int row = f >> 4;
                int c4  = f & 15;
                float4 v = src[f];
                f16x4 hv = {(_Float16)v.x, (_Float16)v.y, (_Float16)v.z, (_Float16)v.w};
                *(f16x4*)&sK[row][c4 * 4] = hv;
            }
        }
        // ---- stage V transposed (each thread a 4x4 sub-block) ----
        {
            const float* vsrc = vb + (size_t)kv * kD;
            int tr = tid >> 4;   // row block 0..15
            int tc = tid & 15;   // col block 0..15
            float4 rv[4];
            #pragma unroll
            for (int j = 0; j < 4; ++j)
                rv[j] = *(const float4*)(vsrc + (size_t)(tr*4 + j) * kD + tc*4);
            #pragma unroll
            for (int cj = 0; cj < 4; ++cj) {
                f16x4 hv = { (_Float16)((&rv[0].x)[cj]), (_Float16)((&rv[1].x)[cj]),
                             (_Float16)((&rv[2].x)[cj]), (_Float16)((&rv[3].x)[cj]) };
                *(f16x4*)&sV[tc*4 + cj][tr*4] = hv;
            }
        }
        __syncthreads();

        #pragma unroll
        for (int g = 0; g < 2; ++g) {
            // ---- QK^T: S[16 x 64] slice for this wave/group ----
            f32x4 s4[4];
            #pragma unroll
            for (int nt = 0; nt < 4; ++nt) {
                s4[nt] = (f32x4){0.f, 0.f, 0.f, 0.f};
                #pragma unroll
                for (int ks = 0; ks < 2; ++ks) {
                    f16x8 kf = *(const f16x8*)&sK[nt*16 + lo][ks*32 + hi*8];
                    s4[nt] = __builtin_amdgcn_mfma_f32_16x16x32_f16(qf[g][ks], kf, s4[nt], 0, 0, 0);
                }
            }
            // ---- online softmax; C/D rows = hi*4 + r ----
            float al[4];
            #pragma unroll
            for (int r = 0; r < 4; ++r) {
                float mx = fmaxf(fmaxf(s4[0][r], s4[1][r]), fmaxf(s4[2][r], s4[3][r]));
                mx = fmaxf(mx, __shfl_xor(mx, 1));
                mx = fmaxf(mx, __shfl_xor(mx, 2));
                mx = fmaxf(mx, __shfl_xor(mx, 4));
                mx = fmaxf(mx, __shfl_xor(mx, 8));
                float mnew = fmaxf(mrow[g][r], mx);
                al[r] = exp2f(mrow[g][r] - mnew);
                mrow[g][r] = mnew;
                float ps = 0.f;
                #pragma unroll
                for (int nt = 0; nt < 4; ++nt) {
                    float p = exp2f(s4[nt][r] - mnew);
                    s4[nt][r] = p;
                    ps += p;
                }
                ps += __shfl_xor(ps, 1); ps += __shfl_xor(ps, 2);
                ps += __shfl_xor(ps, 4); ps += __shfl_xor(ps, 8);
                lrow[g][r] = lrow[g][r] * al[r] + ps;
            }
            // ---- P -> LDS (acc layout -> A-frag layout transpose) ----
            #pragma unroll
            for (int nt = 0; nt < 4; ++nt)
                #pragma unroll
                for (int r = 0; r < 4; ++r)
                    sP[wv][g][hi*4 + r][nt*16 + lo] = (_Float16)s4[nt][r];
            // ---- rescale O ----
            #pragma unroll
            for (int dt = 0; dt < 4; ++dt)
                #pragma unroll
                for (int r = 0; r < 4; ++r)
                    acc[g][dt][r] *= al[r];
            // drain P writes (other lanes' values) before readback
            asm volatile("s_waitcnt lgkmcnt(0)" ::: "memory");
            // ---- PV ----
            #pragma unroll
            for (int kkt = 0; kkt < 2; ++kkt) {
                f16x8 pf = *(const f16x8*)&sP[wv][g][lo][kkt*32 + hi*8];
                #pragma unroll
                for (int dt = 0; dt < 4; ++dt) {
                    f16x8 vf = *(const f16x8*)&sV[dt*16 + lo][kkt*32 + hi*8];
                    acc[g][dt] = __builtin_amdgcn_mfma_f32_16x16x32_f16(pf, vf, acc[g][dt], 0, 0, 0);
                }
            }
        }
    }

    // ---- epilogue: out[b][l][h*64 + d] = O / lsum ----
    #pragma unroll
    for (int g = 0; g < 2; ++g) {
        float inv[4];
        #pragma unroll
        for (int r = 0; r < 4; ++r) inv[r] = 1.f / lrow[g][r];
        #pragma unroll
        for (int dt = 0; dt < 4; ++dt)
            #pragma unroll
            for (int r = 0; r < 4; ++r) {
                int row = q0 + wv*32 + g*16 + hi*4 + r;
                int col = h*kD + dt*16 + lo;
                Og[((size_t)b * kL + row) * (kH * kD) + col] = acc[g][dt][r] * inv[r];
            }
    }
}

extern "C" void kernel_launch(void* const* d_in, const int* in_sizes, int n_in,
                              void* d_out, int out_size, void* d_ws, size_t ws_size,
                              hipStream_t stream) {
    const float* Qg = (const float*)d_in[0];
    const float* Kg = (const float*)d_in[1];
    const float* Vg = (const float*)d_in[2];
    float* Og = (float*)d_out;
    attn_fwd<<<dim3(1024), dim3(256), 0, stream>>>(Qg, Kg, Vg, Og);
}

// Round 2
// 168.403 us; speedup vs baseline: 1.5545x; 1.5545x over previous
//
#include <hip/hip_runtime.h>

typedef _Float16 f16x8 __attribute__((ext_vector_type(8)));
typedef _Float16 f16x4 __attribute__((ext_vector_type(4)));
typedef float    f32x4 __attribute__((ext_vector_type(4)));

namespace {
constexpr int kH = 16, kL = 2048, kD = 64;
constexpr int QBLK  = 128;   // q rows per block (4 waves x 32 rows)
constexpr int KVBLK = 64;    // kv rows per tile
}

__global__ __launch_bounds__(256, 4)
void attn_fwd(const float* __restrict__ Qg, const float* __restrict__ Kg,
              const float* __restrict__ Vg, float* __restrict__ Og)
{
    // 128B rows (power of 2) + XOR swizzle (byte ^= (row&7)<<4) on both sides.
    __shared__ _Float16 sK[KVBLK][64];
    __shared__ _Float16 sV[kD][64];   // V^T with kv-permutation pos() baked in

    const int tid  = threadIdx.x;
    const int wv   = tid >> 6;
    const int lane = tid & 63;
    const int lo   = lane & 15;
    const int hi   = lane >> 4;

    // XCD swizzle: all 16 q-tiles of one (b,h) share an XCD for K/V L2 reuse.
    const int blk  = blockIdx.x;
    const int bh   = (blk & 7) * 8 + (blk >> 7);   // 0..63
    const int qt   = (blk >> 3) & 15;              // 0..15
    const int q0   = qt * QBLK;
    const int b    = bh >> 4;
    const int h    = bh & 15;

    const float QS = 0.125f * 1.44269504088896340736f;  // scale * log2(e)

    // ---- Q fragments (B-operand): B(lane,j) = Q[q=lo(+16g)][d=ks*32+hi*8+j] ----
    f16x8 qf[2][2];  // [row-group g][d-slab ks]
    #pragma unroll
    for (int g = 0; g < 2; ++g) {
        const float* qb = Qg + ((size_t)bh * kL + (q0 + wv*32 + g*16 + lo)) * kD;
        #pragma unroll
        for (int s = 0; s < 2; ++s) {
            const float* p = qb + s*32 + hi*8;
            float4 a0 = *(const float4*)(p);
            float4 a1 = *(const float4*)(p + 4);
            f16x8 q;
            q[0] = (_Float16)(a0.x * QS); q[1] = (_Float16)(a0.y * QS);
            q[2] = (_Float16)(a0.z * QS); q[3] = (_Float16)(a0.w * QS);
            q[4] = (_Float16)(a1.x * QS); q[5] = (_Float16)(a1.y * QS);
            q[6] = (_Float16)(a1.z * QS); q[7] = (_Float16)(a1.w * QS);
            qf[g][s] = q;
        }
    }

    f32x4 acc[2][4];                 // [g][d-tile]; rows q=g*16+hi*4+r, col d=dt*16+lo
    #pragma unroll
    for (int g = 0; g < 2; ++g)
        #pragma unroll
        for (int dt = 0; dt < 4; ++dt) acc[g][dt] = (f32x4){0.f, 0.f, 0.f, 0.f};

    float mrow[2] = {-1e30f, -1e30f};   // per-lane state for q = lo (+16g)
    float lrow[2] = {0.f, 0.f};

    const float* kb = Kg + (size_t)bh * kL * kD;
    const float* vb = Vg + (size_t)bh * kL * kD;

    for (int kv = 0; kv < kL; kv += KVBLK) {
        __syncthreads();
        // ---- stage K tile (fp32 -> fp16, swizzled) ----
        {
            const float4* src = (const float4*)(kb + (size_t)kv * kD);
            #pragma unroll
            for (int i = 0; i < 4; ++i) {
                int f   = tid + i * 256;   // float4 index in 64x64 tile
                int row = f >> 4;
                int c4  = f & 15;
                float4 v = src[f];
                f16x4 hv = {(_Float16)v.x, (_Float16)v.y, (_Float16)v.z, (_Float16)v.w};
                int bo = (c4 * 8) ^ ((row & 7) << 4);
                *(f16x4*)((char*)&sK[row][0] + bo) = hv;
            }
        }
        // ---- stage V transposed + kv-permuted (pos) + swizzled ----
        {
            const float* vsrc = vb + (size_t)kv * kD;
            int tr = tid >> 4;   // kv block 0..15
            int tc = tid & 15;   // d  block 0..15
            float4 rv[4];
            #pragma unroll
            for (int j = 0; j < 4; ++j)
                rv[j] = *(const float4*)(vsrc + (size_t)(tr*4 + j) * kD + tc*4);
            // kv=tr*4+j -> stored byte base: pos(kv)*2 (consecutive in j)
            int posbyte = ((tr >> 3) << 6) + ((tr & 3) << 4) + (((tr >> 2) & 1) << 3);
            #pragma unroll
            for (int cj = 0; cj < 4; ++cj) {
                int row = tc * 4 + cj;   // d row of sV
                f16x4 hv = { (_Float16)((&rv[0].x)[cj]), (_Float16)((&rv[1].x)[cj]),
                             (_Float16)((&rv[2].x)[cj]), (_Float16)((&rv[3].x)[cj]) };
                int bo = posbyte ^ ((row & 7) << 4);
                *(f16x4*)((char*)&sV[row][0] + bo) = hv;
            }
        }
        __syncthreads();

        // ---- hoist V B-fragments (g-invariant): one 16B read each ----
        f16x8 vfrag[2][4];   // [kkt][dt]
        #pragma unroll
        for (int kkt = 0; kkt < 2; ++kkt)
            #pragma unroll
            for (int dt = 0; dt < 4; ++dt) {
                int row = dt*16 + lo;
                int bo = (kkt*64 + hi*16) ^ ((row & 7) << 4);
                vfrag[kkt][dt] = *(const f16x8*)((const char*)&sV[row][0] + bo);
            }

        #pragma unroll
        for (int g = 0; g < 2; ++g) {
            // ---- swapped QK^T: S^T tile; lane holds S[k=nt*16+hi*4+r][q=lo] ----
            f32x4 s4[4];
            #pragma unroll
            for (int nt = 0; nt < 4; ++nt) s4[nt] = (f32x4){0.f, 0.f, 0.f, 0.f};
            #pragma unroll
            for (int ks = 0; ks < 2; ++ks)
                #pragma unroll
                for (int nt = 0; nt < 4; ++nt) {
                    int row = nt*16 + lo;
                    int bo = (ks*64 + hi*16) ^ ((row & 7) << 4);
                    f16x8 kf = *(const f16x8*)((const char*)&sK[row][0] + bo);
                    s4[nt] = __builtin_amdgcn_mfma_f32_16x16x32_f16(kf, qf[g][ks], s4[nt], 0, 0, 0);
                }
            // ---- online softmax for q=lo: own 16 + xor16/32 reduce ----
            float mx = fmaxf(fmaxf(s4[0][0], s4[0][1]), fmaxf(s4[0][2], s4[0][3]));
            #pragma unroll
            for (int nt = 1; nt < 4; ++nt)
                mx = fmaxf(mx, fmaxf(fmaxf(s4[nt][0], s4[nt][1]), fmaxf(s4[nt][2], s4[nt][3])));
            mx = fmaxf(mx, __shfl_xor(mx, 16));
            mx = fmaxf(mx, __shfl_xor(mx, 32));
            float mnew = fmaxf(mrow[g], mx);
            float al = exp2f(mrow[g] - mnew);
            mrow[g] = mnew;
            float ps = 0.f;
            #pragma unroll
            for (int nt = 0; nt < 4; ++nt)
                #pragma unroll
                for (int r = 0; r < 4; ++r) {
                    float p = exp2f(s4[nt][r] - mnew);
                    s4[nt][r] = p;
                    ps += p;
                }
            ps += __shfl_xor(ps, 16);
            ps += __shfl_xor(ps, 32);
            lrow[g] = lrow[g] * al + ps;
            // ---- P A-frags straight from registers (perm matches sV's pos) ----
            f16x8 pf[2];
            #pragma unroll
            for (int kkt = 0; kkt < 2; ++kkt) {
                f16x8 p;
                p[0] = (_Float16)s4[2*kkt][0];   p[1] = (_Float16)s4[2*kkt][1];
                p[2] = (_Float16)s4[2*kkt][2];   p[3] = (_Float16)s4[2*kkt][3];
                p[4] = (_Float16)s4[2*kkt+1][0]; p[5] = (_Float16)s4[2*kkt+1][1];
                p[6] = (_Float16)s4[2*kkt+1][2]; p[7] = (_Float16)s4[2*kkt+1][3];
                pf[kkt] = p;
            }
            // ---- rescale O rows (alpha lives at lane lo=hi*4+r) ----
            float a0 = __shfl(al, hi*4 + 0);
            float a1 = __shfl(al, hi*4 + 1);
            float a2 = __shfl(al, hi*4 + 2);
            float a3 = __shfl(al, hi*4 + 3);
            #pragma unroll
            for (int dt = 0; dt < 4; ++dt) {
                acc[g][dt][0] *= a0; acc[g][dt][1] *= a1;
                acc[g][dt][2] *= a2; acc[g][dt][3] *= a3;
            }
            // ---- PV ----
            #pragma unroll
            for (int kkt = 0; kkt < 2; ++kkt)
                #pragma unroll
                for (int dt = 0; dt < 4; ++dt)
                    acc[g][dt] = __builtin_amdgcn_mfma_f32_16x16x32_f16(pf[kkt], vfrag[kkt][dt], acc[g][dt], 0, 0, 0);
        }
    }

    // ---- epilogue ----
    #pragma unroll
    for (int g = 0; g < 2; ++g) {
        float linv = 1.f / lrow[g];
        float i0 = __shfl(linv, hi*4 + 0);
        float i1 = __shfl(linv, hi*4 + 1);
        float i2 = __shfl(linv, hi*4 + 2);
        float i3 = __shfl(linv, hi*4 + 3);
        #pragma unroll
        for (int dt = 0; dt < 4; ++dt) {
            int col = h*kD + dt*16 + lo;
            int rb  = q0 + wv*32 + g*16 + hi*4;
            Og[((size_t)b * kL + (rb + 0)) * (kH * kD) + col] = acc[g][dt][0] * i0;
            Og[((size_t)b * kL + (rb + 1)) * (kH * kD) + col] = acc[g][dt][1] * i1;
            Og[((size_t)b * kL + (rb + 2)) * (kH * kD) + col] = acc[g][dt][2] * i2;
            Og[((size_t)b * kL + (rb + 3)) * (kH * kD) + col] = acc[g][dt][3] * i3;
        }
    }
}

extern "C" void kernel_launch(void* const* d_in, const int* in_sizes, int n_in,
                              void* d_out, int out_size, void* d_ws, size_t ws_size,
                              hipStream_t stream) {
    const float* Qg = (const float*)d_in[0];
    const float* Kg = (const float*)d_in[1];
    const float* Vg = (const float*)d_in[2];
    float* Og = (float*)d_out;
    attn_fwd<<<dim3(1024), dim3(256), 0, stream>>>(Qg, Kg, Vg, Og);
}

// Round 3
// 142.962 us; speedup vs baseline: 1.8311x; 1.1780x over previous
//
#include <hip/hip_runtime.h>

typedef _Float16 f16x8 __attribute__((ext_vector_type(8)));
typedef _Float16 f16x4 __attribute__((ext_vector_type(4)));
typedef float    f32x4 __attribute__((ext_vector_type(4)));

namespace {
constexpr int kH = 16, kL = 2048, kD = 64;
constexpr int QBLK  = 128;                     // q rows per block (4 waves x 32)
constexpr int KVBLK = 64;                      // kv rows per tile
constexpr int NCHUNK = kL / KVBLK;             // 32
constexpr size_t TILE_BYTES = (size_t)KVBLK * kD * 2;  // 8192
}

#define GLL16(g, l) __builtin_amdgcn_global_load_lds( \
    (const __attribute__((address_space(1))) unsigned int*)(g), \
    (__attribute__((address_space(3))) unsigned int*)(l), 16, 0, 0)

// ---------------- preprocess: K/V fp32 -> fp16 images (swizzle+perm baked) ----
__global__ __launch_bounds__(256, 8)
void prep_kv(const float* __restrict__ K, const float* __restrict__ V,
             _Float16* __restrict__ K16, _Float16* __restrict__ V16)
{
    __shared__ uint4 tile4[512];               // 8KB (V transpose tile)
    char* tileb = (char*)tile4;
    const int tid = threadIdx.x;
    int blk = blockIdx.x;
    if (blk < 64 * NCHUNK) {
        // ---- K tile: fp32 -> fp16, XOR swizzle baked ----
        const float4* src = (const float4*)(K + (size_t)blk * KVBLK * kD);
        char* dst = (char*)K16 + (size_t)blk * TILE_BYTES;
        #pragma unroll
        for (int i = 0; i < 4; ++i) {
            int f = tid + i * 256;             // float4 idx in 64x64 tile
            int row = f >> 4, c4 = f & 15;
            float4 v = src[f];
            f16x4 hv = {(_Float16)v.x, (_Float16)v.y, (_Float16)v.z, (_Float16)v.w};
            *(f16x4*)(dst + row * 128 + ((c4 * 8) ^ ((row & 7) << 4))) = hv;
        }
    } else {
        // ---- V tile: transpose + kv-perm + XOR swizzle, via LDS, coalesced out
        blk -= 64 * NCHUNK;
        const float* vsrc = V + (size_t)blk * KVBLK * kD;
        int tr = tid >> 4, tc = tid & 15;
        float4 rv[4];
        #pragma unroll
        for (int j = 0; j < 4; ++j)
            rv[j] = *(const float4*)(vsrc + (size_t)(tr * 4 + j) * kD + tc * 4);
        int posbyte = ((tr >> 3) << 6) + ((tr & 3) << 4) + (((tr >> 2) & 1) << 3);
        #pragma unroll
        for (int cj = 0; cj < 4; ++cj) {
            int row = tc * 4 + cj;             // d-row of image
            f16x4 hv = { (_Float16)((&rv[0].x)[cj]), (_Float16)((&rv[1].x)[cj]),
                         (_Float16)((&rv[2].x)[cj]), (_Float16)((&rv[3].x)[cj]) };
            *(f16x4*)(tileb + row * 128 + (posbyte ^ ((row & 7) << 4))) = hv;
        }
        __syncthreads();
        uint4* out = (uint4*)((char*)V16 + (size_t)blk * TILE_BYTES);
        out[tid]       = tile4[tid];
        out[tid + 256] = tile4[tid + 256];
    }
}

// ---------------- attention (fp16 images in, 2-phase pipelined) ----------------
__global__ __launch_bounds__(256, 4)
void attn_fwd(const float* __restrict__ Qg, const _Float16* __restrict__ K16,
              const _Float16* __restrict__ V16, float* __restrict__ Og)
{
    __shared__ uint4 sb4[2][1024];             // [buf][ K 8KB | V 8KB ]

    const int tid  = threadIdx.x;
    const int wv   = tid >> 6;
    const int lane = tid & 63;
    const int lo   = lane & 15;
    const int hi   = lane >> 4;
    const int rsw  = (lo & 7) << 4;            // XOR swizzle for frag rows

    const int blk  = blockIdx.x;
    const int bh   = (blk & 7) * 8 + (blk >> 7);
    const int qt   = (blk >> 3) & 15;
    const int q0   = qt * QBLK;
    const int b    = bh >> 4;
    const int h    = bh & 15;

    const float QS = 0.125f * 1.44269504088896340736f;

    // ---- Q fragments (fp32 -> fp16, once per block) ----
    f16x8 qf[2][2];
    #pragma unroll
    for (int g = 0; g < 2; ++g) {
        const float* qb = Qg + ((size_t)bh * kL + (q0 + wv*32 + g*16 + lo)) * kD;
        #pragma unroll
        for (int s = 0; s < 2; ++s) {
            const float* p = qb + s*32 + hi*8;
            float4 a0 = *(const float4*)(p);
            float4 a1 = *(const float4*)(p + 4);
            f16x8 q;
            q[0] = (_Float16)(a0.x * QS); q[1] = (_Float16)(a0.y * QS);
            q[2] = (_Float16)(a0.z * QS); q[3] = (_Float16)(a0.w * QS);
            q[4] = (_Float16)(a1.x * QS); q[5] = (_Float16)(a1.y * QS);
            q[6] = (_Float16)(a1.z * QS); q[7] = (_Float16)(a1.w * QS);
            qf[g][s] = q;
        }
    }

    f32x4 acc[2][4];
    #pragma unroll
    for (int g = 0; g < 2; ++g)
        #pragma unroll
        for (int dt = 0; dt < 4; ++dt) acc[g][dt] = (f32x4){0.f, 0.f, 0.f, 0.f};

    float mrow[2] = {-1e30f, -1e30f};
    float lrow[2] = {0.f, 0.f};

    const char* kbase = (const char*)K16 + (size_t)bh * NCHUNK * TILE_BYTES;
    const char* vbase = (const char*)V16 + (size_t)bh * NCHUNK * TILE_BYTES;

    auto stage = [&](int bufi, int t) {
        const char* ks = kbase + (size_t)t * TILE_BYTES + wv*2048 + lane*16;
        const char* vs = vbase + (size_t)t * TILE_BYTES + wv*2048 + lane*16;
        char* kd = (char*)sb4[bufi] + wv*2048;
        char* vd = (char*)sb4[bufi] + TILE_BYTES + wv*2048;
        GLL16(ks,        kd);
        GLL16(ks + 1024, kd + 1024);
        GLL16(vs,        vd);
        GLL16(vs + 1024, vd + 1024);
    };

    stage(0, 0);
    asm volatile("s_waitcnt vmcnt(0)" ::: "memory");
    __syncthreads();

    for (int t = 0; t < NCHUNK; ++t) {
        const int cur = t & 1;
        if (t + 1 < NCHUNK) stage(cur ^ 1, t + 1);
        const char* sK = (const char*)sb4[cur];
        const char* sV = (const char*)sb4[cur] + TILE_BYTES;

        // ---- hoist V B-fragments (g-invariant) ----
        f16x8 vfrag[2][4];
        #pragma unroll
        for (int kkt = 0; kkt < 2; ++kkt) {
            const int off = (kkt*64 + hi*16) ^ rsw;
            #pragma unroll
            for (int dt = 0; dt < 4; ++dt)
                vfrag[kkt][dt] = *(const f16x8*)(sV + dt*2048 + lo*128 + off);
        }

        #pragma unroll
        for (int g = 0; g < 2; ++g) {
            // ---- swapped QK^T ----
            f32x4 s4[4];
            #pragma unroll
            for (int nt = 0; nt < 4; ++nt) s4[nt] = (f32x4){0.f, 0.f, 0.f, 0.f};
            __builtin_amdgcn_s_setprio(1);
            #pragma unroll
            for (int ks = 0; ks < 2; ++ks) {
                const int off = (ks*64 + hi*16) ^ rsw;
                #pragma unroll
                for (int nt = 0; nt < 4; ++nt) {
                    f16x8 kf = *(const f16x8*)(sK + nt*2048 + lo*128 + off);
                    s4[nt] = __builtin_amdgcn_mfma_f32_16x16x32_f16(kf, qf[g][ks], s4[nt], 0, 0, 0);
                }
            }
            __builtin_amdgcn_s_setprio(0);
            // ---- online softmax (q = lo), T13 defer-rescale ----
            float mx = fmaxf(fmaxf(s4[0][0], s4[0][1]), fmaxf(s4[0][2], s4[0][3]));
            #pragma unroll
            for (int nt = 1; nt < 4; ++nt)
                mx = fmaxf(mx, fmaxf(fmaxf(s4[nt][0], s4[nt][1]), fmaxf(s4[nt][2], s4[nt][3])));
            mx = fmaxf(mx, __shfl_xor(mx, 16));
            mx = fmaxf(mx, __shfl_xor(mx, 32));
            if (!__all(mx <= mrow[g] + 8.f)) {
                float mnew = fmaxf(mrow[g], mx);
                float al = exp2f(mrow[g] - mnew);
                mrow[g] = mnew;
                lrow[g] *= al;
                float a0 = __shfl(al, hi*4 + 0);
                float a1 = __shfl(al, hi*4 + 1);
                float a2 = __shfl(al, hi*4 + 2);
                float a3 = __shfl(al, hi*4 + 3);
                #pragma unroll
                for (int dt = 0; dt < 4; ++dt) {
                    acc[g][dt][0] *= a0; acc[g][dt][1] *= a1;
                    acc[g][dt][2] *= a2; acc[g][dt][3] *= a3;
                }
            }
            float ps = 0.f;
            #pragma unroll
            for (int nt = 0; nt < 4; ++nt)
                #pragma unroll
                for (int r = 0; r < 4; ++r) {
                    float p = exp2f(s4[nt][r] - mrow[g]);
                    s4[nt][r] = p;
                    ps += p;
                }
            ps += __shfl_xor(ps, 16);
            ps += __shfl_xor(ps, 32);
            lrow[g] += ps;
            // ---- P A-frags from registers ----
            f16x8 pf[2];
            #pragma unroll
            for (int kkt = 0; kkt < 2; ++kkt) {
                f16x8 p;
                p[0] = (_Float16)s4[2*kkt][0];   p[1] = (_Float16)s4[2*kkt][1];
                p[2] = (_Float16)s4[2*kkt][2];   p[3] = (_Float16)s4[2*kkt][3];
                p[4] = (_Float16)s4[2*kkt+1][0]; p[5] = (_Float16)s4[2*kkt+1][1];
                p[6] = (_Float16)s4[2*kkt+1][2]; p[7] = (_Float16)s4[2*kkt+1][3];
                pf[kkt] = p;
            }
            // ---- PV ----
            __builtin_amdgcn_s_setprio(1);
            #pragma unroll
            for (int kkt = 0; kkt < 2; ++kkt)
                #pragma unroll
                for (int dt = 0; dt < 4; ++dt)
                    acc[g][dt] = __builtin_amdgcn_mfma_f32_16x16x32_f16(pf[kkt], vfrag[kkt][dt], acc[g][dt], 0, 0, 0);
            __builtin_amdgcn_s_setprio(0);
        }
        asm volatile("s_waitcnt vmcnt(0)" ::: "memory");
        __syncthreads();
    }

    // ---- epilogue ----
    #pragma unroll
    for (int g = 0; g < 2; ++g) {
        float linv = 1.f / lrow[g];
        float i0 = __shfl(linv, hi*4 + 0);
        float i1 = __shfl(linv, hi*4 + 1);
        float i2 = __shfl(linv, hi*4 + 2);
        float i3 = __shfl(linv, hi*4 + 3);
        #pragma unroll
        for (int dt = 0; dt < 4; ++dt) {
            int col = h*kD + dt*16 + lo;
            int rb  = q0 + wv*32 + g*16 + hi*4;
            Og[((size_t)b * kL + (rb + 0)) * (kH * kD) + col] = acc[g][dt][0] * i0;
            Og[((size_t)b * kL + (rb + 1)) * (kH * kD) + col] = acc[g][dt][1] * i1;
            Og[((size_t)b * kL + (rb + 2)) * (kH * kD) + col] = acc[g][dt][2] * i2;
            Og[((size_t)b * kL + (rb + 3)) * (kH * kD) + col] = acc[g][dt][3] * i3;
        }
    }
}

// ---------------- fallback (round-2 kernel) if ws too small ----------------
__global__ __launch_bounds__(256, 4)
void attn_fwd_fb(const float* __restrict__ Qg, const float* __restrict__ Kg,
                 const float* __restrict__ Vg, float* __restrict__ Og)
{
    __shared__ _Float16 sK[KVBLK][64];
    __shared__ _Float16 sV[kD][64];

    const int tid  = threadIdx.x;
    const int wv   = tid >> 6;
    const int lane = tid & 63;
    const int lo   = lane & 15;
    const int hi   = lane >> 4;

    const int blk  = blockIdx.x;
    const int bh   = (blk & 7) * 8 + (blk >> 7);
    const int qt   = (blk >> 3) & 15;
    const int q0   = qt * QBLK;
    const int b    = bh >> 4;
    const int h    = bh & 15;

    const float QS = 0.125f * 1.44269504088896340736f;

    f16x8 qf[2][2];
    #pragma unroll
    for (int g = 0; g < 2; ++g) {
        const float* qb = Qg + ((size_t)bh * kL + (q0 + wv*32 + g*16 + lo)) * kD;
        #pragma unroll
        for (int s = 0; s < 2; ++s) {
            const float* p = qb + s*32 + hi*8;
            float4 a0 = *(const float4*)(p);
            float4 a1 = *(const float4*)(p + 4);
            f16x8 q;
            q[0] = (_Float16)(a0.x * QS); q[1] = (_Float16)(a0.y * QS);
            q[2] = (_Float16)(a0.z * QS); q[3] = (_Float16)(a0.w * QS);
            q[4] = (_Float16)(a1.x * QS); q[5] = (_Float16)(a1.y * QS);
            q[6] = (_Float16)(a1.z * QS); q[7] = (_Float16)(a1.w * QS);
            qf[g][s] = q;
        }
    }

    f32x4 acc[2][4];
    #pragma unroll
    for (int g = 0; g < 2; ++g)
        #pragma unroll
        for (int dt = 0; dt < 4; ++dt) acc[g][dt] = (f32x4){0.f, 0.f, 0.f, 0.f};

    float mrow[2] = {-1e30f, -1e30f};
    float lrow[2] = {0.f, 0.f};

    const float* kb = Kg + (size_t)bh * kL * kD;
    const float* vb = Vg + (size_t)bh * kL * kD;

    for (int kv = 0; kv < kL; kv += KVBLK) {
        __syncthreads();
        {
            const float4* src = (const float4*)(kb + (size_t)kv * kD);
            #pragma unroll
            for (int i = 0; i < 4; ++i) {
                int f   = tid + i * 256;
                int row = f >> 4;
                int c4  = f & 15;
                float4 v = src[f];
                f16x4 hv = {(_Float16)v.x, (_Float16)v.y, (_Float16)v.z, (_Float16)v.w};
                int bo = (c4 * 8) ^ ((row & 7) << 4);
                *(f16x4*)((char*)&sK[row][0] + bo) = hv;
            }
        }
        {
            const float* vsrc = vb + (size_t)kv * kD;
            int tr = tid >> 4;
            int tc = tid & 15;
            float4 rv[4];
            #pragma unroll
            for (int j = 0; j < 4; ++j)
                rv[j] = *(const float4*)(vsrc + (size_t)(tr*4 + j) * kD + tc*4);
            int posbyte = ((tr >> 3) << 6) + ((tr & 3) << 4) + (((tr >> 2) & 1) << 3);
            #pragma unroll
            for (int cj = 0; cj < 4; ++cj) {
                int row = tc * 4 + cj;
                f16x4 hv = { (_Float16)((&rv[0].x)[cj]), (_Float16)((&rv[1].x)[cj]),
                             (_Float16)((&rv[2].x)[cj]), (_Float16)((&rv[3].x)[cj]) };
                int bo = posbyte ^ ((row & 7) << 4);
                *(f16x4*)((char*)&sV[row][0] + bo) = hv;
            }
        }
        __syncthreads();

        f16x8 vfrag[2][4];
        #pragma unroll
        for (int kkt = 0; kkt < 2; ++kkt)
            #pragma unroll
            for (int dt = 0; dt < 4; ++dt) {
                int row = dt*16 + lo;
                int bo = (kkt*64 + hi*16) ^ ((row & 7) << 4);
                vfrag[kkt][dt] = *(const f16x8*)((const char*)&sV[row][0] + bo);
            }

        #pragma unroll
        for (int g = 0; g < 2; ++g) {
            f32x4 s4[4];
            #pragma unroll
            for (int nt = 0; nt < 4; ++nt) s4[nt] = (f32x4){0.f, 0.f, 0.f, 0.f};
            #pragma unroll
            for (int ks = 0; ks < 2; ++ks)
                #pragma unroll
                for (int nt = 0; nt < 4; ++nt) {
                    int row = nt*16 + lo;
                    int bo = (ks*64 + hi*16) ^ ((row & 7) << 4);
                    f16x8 kf = *(const f16x8*)((const char*)&sK[row][0] + bo);
                    s4[nt] = __builtin_amdgcn_mfma_f32_16x16x32_f16(kf, qf[g][ks], s4[nt], 0, 0, 0);
                }
            float mx = fmaxf(fmaxf(s4[0][0], s4[0][1]), fmaxf(s4[0][2], s4[0][3]));
            #pragma unroll
            for (int nt = 1; nt < 4; ++nt)
                mx = fmaxf(mx, fmaxf(fmaxf(s4[nt][0], s4[nt][1]), fmaxf(s4[nt][2], s4[nt][3])));
            mx = fmaxf(mx, __shfl_xor(mx, 16));
            mx = fmaxf(mx, __shfl_xor(mx, 32));
            float mnew = fmaxf(mrow[g], mx);
            float al = exp2f(mrow[g] - mnew);
            mrow[g] = mnew;
            float ps = 0.f;
            #pragma unroll
            for (int nt = 0; nt < 4; ++nt)
                #pragma unroll
                for (int r = 0; r < 4; ++r) {
                    float p = exp2f(s4[nt][r] - mnew);
                    s4[nt][r] = p;
                    ps += p;
                }
            ps += __shfl_xor(ps, 16);
            ps += __shfl_xor(ps, 32);
            lrow[g] = lrow[g] * al + ps;
            f16x8 pf[2];
            #pragma unroll
            for (int kkt = 0; kkt < 2; ++kkt) {
                f16x8 p;
                p[0] = (_Float16)s4[2*kkt][0];   p[1] = (_Float16)s4[2*kkt][1];
                p[2] = (_Float16)s4[2*kkt][2];   p[3] = (_Float16)s4[2*kkt][3];
                p[4] = (_Float16)s4[2*kkt+1][0]; p[5] = (_Float16)s4[2*kkt+1][1];
                p[6] = (_Float16)s4[2*kkt+1][2]; p[7] = (_Float16)s4[2*kkt+1][3];
                pf[kkt] = p;
            }
            float a0 = __shfl(al, hi*4 + 0);
            float a1 = __shfl(al, hi*4 + 1);
            float a2 = __shfl(al, hi*4 + 2);
            float a3 = __shfl(al, hi*4 + 3);
            #pragma unroll
            for (int dt = 0; dt < 4; ++dt) {
                acc[g][dt][0] *= a0; acc[g][dt][1] *= a1;
                acc[g][dt][2] *= a2; acc[g][dt][3] *= a3;
            }
            #pragma unroll
            for (int kkt = 0; kkt < 2; ++kkt)
                #pragma unroll
                for (int dt = 0; dt < 4; ++dt)
                    acc[g][dt] = __builtin_amdgcn_mfma_f32_16x16x32_f16(pf[kkt], vfrag[kkt][dt], acc[g][dt], 0, 0, 0);
        }
    }

    #pragma unroll
    for (int g = 0; g < 2; ++g) {
        float linv = 1.f / lrow[g];
        float i0 = __shfl(linv, hi*4 + 0);
        float i1 = __shfl(linv, hi*4 + 1);
        float i2 = __shfl(linv, hi*4 + 2);
        float i3 = __shfl(linv, hi*4 + 3);
        #pragma unroll
        for (int dt = 0; dt < 4; ++dt) {
            int col = h*kD + dt*16 + lo;
            int rb  = q0 + wv*32 + g*16 + hi*4;
            Og[((size_t)b * kL + (rb + 0)) * (kH * kD) + col] = acc[g][dt][0] * i0;
            Og[((size_t)b * kL + (rb + 1)) * (kH * kD) + col] = acc[g][dt][1] * i1;
            Og[((size_t)b * kL + (rb + 2)) * (kH * kD) + col] = acc[g][dt][2] * i2;
            Og[((size_t)b * kL + (rb + 3)) * (kH * kD) + col] = acc[g][dt][3] * i3;
        }
    }
}

extern "C" void kernel_launch(void* const* d_in, const int* in_sizes, int n_in,
                              void* d_out, int out_size, void* d_ws, size_t ws_size,
                              hipStream_t stream) {
    const float* Qg = (const float*)d_in[0];
    const float* Kg = (const float*)d_in[1];
    const float* Vg = (const float*)d_in[2];
    float* Og = (float*)d_out;

    const size_t imgElems = (size_t)64 * kL * kD;         // 8M halves = 16MB
    if (ws_size >= imgElems * 2 * sizeof(_Float16)) {
        _Float16* K16 = (_Float16*)d_ws;
        _Float16* V16 = K16 + imgElems;
        prep_kv<<<dim3(2 * 64 * NCHUNK), dim3(256), 0, stream>>>(Kg, Vg, K16, V16);
        attn_fwd<<<dim3(1024), dim3(256), 0, stream>>>(Qg, K16, V16, Og);
    } else {
        attn_fwd_fb<<<dim3(1024), dim3(256), 0, stream>>>(Qg, Kg, Vg, Og);
    }
}